// Round 7
// baseline (214.643 us; speedup 1.0000x reference)
//
#include <hip/hip_runtime.h>

#define GAMMA 0.01f
#define INV_GAMMA 100.0f
#define B 32
#define G 2048
#define C 16
#define S 8
#define L 3
#define M 16
#define NB 256          // 32 b x 8 tiles; == CU count
#define TPB 512
#define TILE 256        // g per block
#define POISON 0xAAAAAAAAu   // harness poisons d_ws; posted maxes are >=0 (sign bit 0)

__device__ __forceinline__ float waveMax(float v) {
#pragma unroll
    for (int off = 32; off > 0; off >>= 1)
        v = fmaxf(v, __shfl_xor(v, off, 64));
    return v;
}

// 512-thread block max, broadcast. Leading guard sync makes repeated use safe.
__device__ __forceinline__ float blockMaxBcast(float v, float* scratch8) {
    float wm = waveMax(v);
    __syncthreads();
    if ((threadIdx.x & 63) == 0) scratch8[threadIdx.x >> 6] = wm;
    __syncthreads();
    float r = fmaxf(fmaxf(scratch8[0], scratch8[1]), fmaxf(scratch8[2], scratch8[3]));
    return fmaxf(r, fmaxf(fmaxf(scratch8[4], scratch8[5]), fmaxf(scratch8[6], scratch8[7])));
}

__device__ __forceinline__ void postSlot(unsigned* slot, float bm) {
    if (threadIdx.x == 0)   // release: drains this wave's prior stores; other waves'
                            // Ry stores were drained by the preceding __syncthreads
        __hip_atomic_store(slot, __float_as_uint(bm),
                           __ATOMIC_RELEASE, __HIP_MEMORY_SCOPE_AGENT);
}

// Reducer (block-uniform call): wave 7 polls all NB slots (4/lane, coalesced,
// sole reader of these lines), wave-reduces, posts the single-writer Result word.
// No syncthreads inside — other waves keep working and re-join at the next sync.
__device__ __forceinline__ void reduceEvent(const unsigned* __restrict__ slots,
                                            unsigned* __restrict__ result) {
    const int t = threadIdx.x;
    if (t >= TPB - 64) {
        const int l = t - (TPB - 64);
        unsigned u0, u1, u2, u3;
        for (;;) {
            u0 = __hip_atomic_load(&slots[l],       __ATOMIC_RELAXED, __HIP_MEMORY_SCOPE_AGENT);
            u1 = __hip_atomic_load(&slots[l + 64],  __ATOMIC_RELAXED, __HIP_MEMORY_SCOPE_AGENT);
            u2 = __hip_atomic_load(&slots[l + 128], __ATOMIC_RELAXED, __HIP_MEMORY_SCOPE_AGENT);
            u3 = __hip_atomic_load(&slots[l + 192], __ATOMIC_RELAXED, __HIP_MEMORY_SCOPE_AGENT);
            if (u0 != POISON && u1 != POISON && u2 != POISON && u3 != POISON) break;
            __builtin_amdgcn_s_sleep(1);
        }
        float v = fmaxf(fmaxf(__uint_as_float(u0), __uint_as_float(u1)),
                        fmaxf(__uint_as_float(u2), __uint_as_float(u3)));
        v = waveMax(v);
        if (l == 0)
            __hip_atomic_store(result, __float_as_uint(v),
                               __ATOMIC_RELEASE, __HIP_MEMORY_SCOPE_AGENT);
    }
}

// Consumer: thread 0 polls the (write-once) Result word, LDS-broadcast.
__device__ __forceinline__ float waitResult(const unsigned* __restrict__ result,
                                            float* bcast) {
    if (threadIdx.x == 0) {
        unsigned u = __hip_atomic_load(result, __ATOMIC_RELAXED, __HIP_MEMORY_SCOPE_AGENT);
        while (u == POISON) {
            __builtin_amdgcn_s_sleep(1);
            u = __hip_atomic_load(result, __ATOMIC_RELAXED, __HIP_MEMORY_SCOPE_AGENT);
        }
        *bcast = __uint_as_float(u);
    }
    __syncthreads();
    return *bcast;
}

__global__ __launch_bounds__(TPB, 1) void fused(
    const float* __restrict__ x, const float* __restrict__ W,
    const int* __restrict__ I, float* __restrict__ out,
    unsigned* __restrict__ Slots, unsigned* __restrict__ Result,
    float* __restrict__ Ry) {
    __shared__ float Vrow[G];        // 8 KB, RAW (unscaled) V row b
    __shared__ float CvL[C][TILE];   // 16 KB
    __shared__ float WsL[M * C];     // 1 KB
    __shared__ float scratch8[8];
    __shared__ float bcast;

    const int t   = threadIdx.x;
    const int blk = blockIdx.x;
    const int b   = blk >> 3;
    const int g0  = (blk & 7) * TILE;
    const int gl  = t & 255;
    const int ch  = (t >> 8) * 8;    // this thread's c-half base

    // Ws = softmax(W, axis=1), redundant per block (first read after later syncs)
    if (t < M * C) {
        int m = t >> 4, c = t & 15;
        float rmax = -INFINITY;
#pragma unroll
        for (int j = 0; j < C; j++) rmax = fmaxf(rmax, W[m * C + j]);
        float rsum = 0.f;
#pragma unroll
        for (int j = 0; j < C; j++) rsum += __expf(W[m * C + j] - rmax);
        WsL[t] = __expf(W[m * C + c] - rmax) / rsum;
    }

    float Rreg = (t < TILE) ? x[(size_t)b * G + g0 + t] : 0.f;  // unscaled y
    float s3 = 1.0f;

    // ---- Prologue: stage raw x row, compute praw for it=0 (no sync needed) ----
    ((float4*)Vrow)[t] = ((const float4*)(x + (size_t)b * G))[t];   // 8 KB
    __syncthreads();

    float praw[8][S];   // raw gather-products for my 8 c's (s3-independent)
#pragma unroll 2
    for (int cc = 0; cc < 8; cc++) {
        const int4* ip = (const int4*)(I + ((size_t)(ch + cc) * G + g0 + gl) * (S * L));
        int idx[S * L];
#pragma unroll
        for (int q = 0; q < 6; q++) {
            int4 v = ip[q];
            idx[q * 4 + 0] = v.x; idx[q * 4 + 1] = v.y;
            idx[q * 4 + 2] = v.z; idx[q * 4 + 3] = v.w;
        }
#pragma unroll
        for (int ss = 0; ss < S; ss++)
            praw[cc][ss] = Vrow[idx[ss * 3]] * Vrow[idx[ss * 3 + 1]] * Vrow[idx[ss * 3 + 2]];
    }

    for (int it = 0; it < 5; ++it) {
        const int eA = it * 3, eB = it * 3 + 1, eC = it * 3 + 2;

        // ---- Phase A (cheap part): Cv = gamma*lse_s(s3^3 * praw) ----
        const float s3c = s3 * s3 * s3;
        float ymax = -INFINITY;
#pragma unroll
        for (int cc = 0; cc < 8; cc++) {
            float bm = praw[cc][0];
#pragma unroll
            for (int ss = 1; ss < S; ss++) bm = fmaxf(bm, praw[cc][ss]);
            float sum = 0.f;
#pragma unroll
            for (int ss = 0; ss < S; ss++)
                sum += __expf((praw[cc][ss] - bm) * (s3c * INV_GAMMA));
            float y = s3c * bm + GAMMA * __logf(sum);
            CvL[ch + cc][gl] = y;
            ymax = fmaxf(ymax, y);
        }
        float bmA = blockMaxBcast(ymax, scratch8);   // also publishes CvL
        postSlot(&Slots[eA * NB + blk], bmA);
        if (blk == eA) reduceEvent(&Slots[eA * NB], &Result[eA * 32]);

        // ---- overlap barrier A: Hraw = Ws @ Cv (linear, s1-free) ----
        float Hraw[M], hmr = -INFINITY;
        if (t < TILE) {
            float cv[C];
#pragma unroll
            for (int c = 0; c < C; c++) cv[c] = CvL[c][t];
#pragma unroll
            for (int m = 0; m < M; m++) {
                float acc = 0.f;
#pragma unroll
                for (int c = 0; c < C; c++) acc = fmaf(WsL[m * C + c], cv[c], acc);
                Hraw[m] = acc; hmr = fmaxf(hmr, acc);
            }
        }
        float m1 = waitResult(&Result[eA * 32], &bcast);
        float s1 = (m1 > 1.0f) ? 1.0f / m1 : 1.0f;

        // ---- Phase B: Hy = softor_M(s1 * Hraw) ----
        float hy = -INFINITY;
        if (t < TILE) {
            float sum = 0.f;
#pragma unroll
            for (int m = 0; m < M; m++)
                sum += __expf((Hraw[m] - hmr) * (s1 * INV_GAMMA));
            hy = s1 * hmr + GAMMA * __logf(sum);
        }
        float bmB = blockMaxBcast(hy, scratch8);
        postSlot(&Slots[eB * NB + blk], bmB);
        if (blk == eB) reduceEvent(&Slots[eB * NB], &Result[eB * 32]);
        float m2 = waitResult(&Result[eB * 32], &bcast);
        float s2 = (m2 > 1.0f) ? 1.0f / m2 : 1.0f;

        // ---- Phase C: R_new = softor_2(s3*R, s2*Hy) ----
        float ynew = -INFINITY;
        if (t < TILE) {
            float Rv = s3 * Rreg;
            float rv = s2 * hy;
            float a = fmaxf(Rv, rv), d = fminf(Rv, rv);
            ynew = a + GAMMA * __logf(1.0f + __expf((d - a) * INV_GAMMA));
            Rreg = ynew;
            if (it < 4)   // agent store; drained by blockMaxBcast's pre-barrier vmcnt(0)
                __hip_atomic_store(&Ry[(size_t)b * G + g0 + t], ynew,
                                   __ATOMIC_RELAXED, __HIP_MEMORY_SCOPE_AGENT);
        }
        float bmC = blockMaxBcast(ynew, scratch8);
        postSlot(&Slots[eC * NB + blk], bmC);
        if (blk == eC) reduceEvent(&Slots[eC * NB], &Result[eC * 32]);

        // ---- overlap barrier C: wait only row b's 8 producers, then stage raw
        //      Ry and compute next praw (s3-independent) while global max settles
        if (it < 4) {
            if (t < 8) {
                const unsigned* p = &Slots[eC * NB + b * 8 + t];
                unsigned u = __hip_atomic_load(p, __ATOMIC_RELAXED, __HIP_MEMORY_SCOPE_AGENT);
                while (u == POISON) {
                    __builtin_amdgcn_s_sleep(1);
                    u = __hip_atomic_load(p, __ATOMIC_RELAXED, __HIP_MEMORY_SCOPE_AGENT);
                }
            }
            __syncthreads();   // row b's Ry now visible (producers posted after drain)
            if (t < TILE) {
#pragma unroll
                for (int k = 0; k < 8; k++) {
                    int j = t + k * TILE;
                    Vrow[j] = __hip_atomic_load(&Ry[(size_t)b * G + j],
                                                __ATOMIC_RELAXED, __HIP_MEMORY_SCOPE_AGENT);
                }
            }
            __syncthreads();
#pragma unroll 2
            for (int cc = 0; cc < 8; cc++) {
                const int4* ip = (const int4*)(I + ((size_t)(ch + cc) * G + g0 + gl) * (S * L));
                int idx[S * L];
#pragma unroll
                for (int q = 0; q < 6; q++) {
                    int4 v = ip[q];
                    idx[q * 4 + 0] = v.x; idx[q * 4 + 1] = v.y;
                    idx[q * 4 + 2] = v.z; idx[q * 4 + 3] = v.w;
                }
#pragma unroll
                for (int ss = 0; ss < S; ss++)
                    praw[cc][ss] = Vrow[idx[ss * 3]] * Vrow[idx[ss * 3 + 1]] * Vrow[idx[ss * 3 + 2]];
            }
        }
        float m3 = waitResult(&Result[eC * 32], &bcast);
        s3 = (m3 > 1.0f) ? 1.0f / m3 : 1.0f;
    }

    if (t < TILE) out[(size_t)b * G + g0 + t] = s3 * Rreg;
}

extern "C" void kernel_launch(void* const* d_in, const int* in_sizes, int n_in,
                              void* d_out, int out_size, void* d_ws, size_t ws_size,
                              hipStream_t stream) {
    const float* x = (const float*)d_in[0];   // (B,G)
    const float* W = (const float*)d_in[1];   // (M,C)
    const int*   I = (const int*)d_in[2];     // (C,G,S,L)
    float* out = (float*)d_out;

    unsigned* ws     = (unsigned*)d_ws;
    unsigned* Slots  = ws;                    // 15 * 256 (poisoned 0xAA by harness)
    unsigned* Result = ws + 15 * NB;          // 15 events, padded 32 words (1 line) apart
    float*    Ry     = (float*)(ws + 15 * NB + 15 * 32 + 32);   // B*G

    // grid(256) == CU count -> 1 block/CU, all co-resident; dataflow slot sync.
    fused<<<dim3(NB), dim3(TPB), 0, stream>>>(x, W, I, out, Slots, Result, Ry);
}